// Round 6
// baseline (158.515 us; speedup 1.0000x reference)
//
#include <hip/hip_runtime.h>
#include <hip/hip_bf16.h>

#define NH 16
#define DH 64
#define DM 1024
#define NC 2048
#define MROWS 4096
#define KVT 64

#define SCALE_Q 0.180336880f   // 0.125 * log2(e): softmax done in 2^x domain

typedef __attribute__((ext_vector_type(8))) short short8;
typedef __attribute__((ext_vector_type(4))) float f32x4;
typedef __attribute__((ext_vector_type(16))) float f32x16;
typedef __attribute__((ext_vector_type(4))) unsigned int uint4e;

__device__ __forceinline__ unsigned pkbf16(float a, float b) {
    unsigned r;
    asm("v_cvt_pk_bf16_f32 %0, %1, %2" : "=v"(r) : "v"(a), "v"(b));
    return r;
}
__device__ __forceinline__ unsigned short f2bf(float x) {
    return (unsigned short)(pkbf16(x, x) & 0xffffu);
}
__device__ __forceinline__ float exp2v(float x) {   // 2^x, v_exp_f32
    float r;
    asm("v_exp_f32 %0, %1" : "=v"(r) : "v"(x));
    return r;
}
__device__ __forceinline__ f32x16 fzero16() {
    f32x16 r;
    #pragma unroll
    for (int i = 0; i < 16; ++i) r[i] = 0.f;
    return r;
}
__device__ __forceinline__ short8 mk8(unsigned w0, unsigned w1, unsigned w2, unsigned w3) {
    uint4e u = {w0, w1, w2, w3};
    return __builtin_bit_cast(short8, u);
}
// async global->LDS, 16B per lane; lds dest must be wave-uniform base (+lane*16 by HW)
__device__ __forceinline__ void gload16(const unsigned short* g, unsigned short* l) {
    __builtin_amdgcn_global_load_lds(
        (const __attribute__((address_space(1))) void*)g,
        (__attribute__((address_space(3))) void*)l, 16, 0, 0);
}

// ---------------------------------------------------------------------------
// fp32 -> bf16 elementwise convert (8 elems/thread)
// ---------------------------------------------------------------------------
__global__ __launch_bounds__(256) void cvt_x(const float* __restrict__ in,
                                             unsigned short* __restrict__ out, int n8)
{
    int i = blockIdx.x * 256 + threadIdx.x;
    if (i >= n8) return;
    const float4 a = ((const float4*)in)[i * 2];
    const float4 b = ((const float4*)in)[i * 2 + 1];
    uint4e u = {pkbf16(a.x, a.y), pkbf16(a.z, a.w), pkbf16(b.x, b.y), pkbf16(b.z, b.w)};
    ((uint4e*)out)[i] = u;
}

// ---------------------------------------------------------------------------
// All 4 weights: W[K][N] fp32 -> Wt[N][K] bf16, fused (blockIdx.z = which W)
// ---------------------------------------------------------------------------
__global__ __launch_bounds__(256) void cvt_w4(const float* __restrict__ W0,
                                              const float* __restrict__ W1,
                                              const float* __restrict__ W2,
                                              const float* __restrict__ W3,
                                              unsigned short* __restrict__ Wt4)
{
    __shared__ unsigned short T[64][72];
    const int z = blockIdx.z;
    const float* W = (z == 0) ? W0 : (z == 1) ? W1 : (z == 2) ? W2 : W3;
    unsigned short* Wt = Wt4 + (size_t)z * DM * DM;
    const int t = threadIdx.x;
    const int r = t >> 2, s = t & 3;
    const int bi = blockIdx.y;
    const int bj = blockIdx.x;
    const float* src = W + (size_t)(bi * 64 + r) * DM + bj * 64 + s * 16;
    float4 f0 = ((const float4*)src)[0];
    float4 f1 = ((const float4*)src)[1];
    float4 f2 = ((const float4*)src)[2];
    float4 f3 = ((const float4*)src)[3];
    uint2 u;
    u.x = pkbf16(f0.x, f0.y); u.y = pkbf16(f0.z, f0.w); *(uint2*)&T[r][s * 16]      = u;
    u.x = pkbf16(f1.x, f1.y); u.y = pkbf16(f1.z, f1.w); *(uint2*)&T[r][s * 16 + 4]  = u;
    u.x = pkbf16(f2.x, f2.y); u.y = pkbf16(f2.z, f2.w); *(uint2*)&T[r][s * 16 + 8]  = u;
    u.x = pkbf16(f3.x, f3.y); u.y = pkbf16(f3.z, f3.w); *(uint2*)&T[r][s * 16 + 12] = u;
    __syncthreads();
    unsigned short vals[16];
    #pragma unroll
    for (int j = 0; j < 16; ++j) vals[j] = T[s * 16 + j][r];
    unsigned short* dst = Wt + (size_t)(bj * 64 + r) * DM + bi * 64 + s * 16;
    *(short8*)(dst)     = *(short8*)&vals[0];
    *(short8*)(dst + 8) = *(short8*)&vals[8];
}

// ---------------------------------------------------------------------------
// V [4096][1024] bf16 -> Vt[bh*64 + d][n] bf16 (per-head transpose), 64x64 tiles
// ---------------------------------------------------------------------------
__global__ __launch_bounds__(256) void cvt_vT(const unsigned short* __restrict__ V,
                                              unsigned short* __restrict__ Vt)
{
    __shared__ unsigned short T[64][72];
    const int t  = threadIdx.x;
    const int nx = blockIdx.x;        // 0..31 (n tile)
    const int bh = blockIdx.y;        // 0..31
    const int b  = bh >> 4, h = bh & 15;
    const int n0 = nx << 6;
    const int r  = t >> 2, s = t & 3;
    const unsigned short* src = V + ((size_t)b * NC + n0 + r) * DM + h * 64 + s * 16;
    *(short8*)&T[r][s * 16]     = *(const short8*)(src);
    *(short8*)&T[r][s * 16 + 8] = *(const short8*)(src + 8);
    __syncthreads();
    unsigned short vals[16];
    #pragma unroll
    for (int j = 0; j < 16; ++j) vals[j] = T[s * 16 + j][r];
    unsigned short* dst = Vt + ((size_t)bh * 64 + r) * NC + n0 + s * 16;
    *(short8*)(dst)     = *(short8*)&vals[0];
    *(short8*)(dst + 8) = *(short8*)&vals[8];
}

// ---------------------------------------------------------------------------
// Fused QKV projection (m97 structure): 128x128 tile, BK=32, 4 waves,
// global_load_lds width-16 staging into LINEAR LDS [128][32] shorts.
// Q segment pre-scaled by SCALE_Q.
// ---------------------------------------------------------------------------
__global__ __launch_bounds__(256) void gemm_qkv(const unsigned short* __restrict__ A,
                                                const unsigned short* __restrict__ Bt,
                                                const float* __restrict__ bq,
                                                const float* __restrict__ bk,
                                                const float* __restrict__ bv,
                                                unsigned short* __restrict__ Out)
{
    __shared__ unsigned short As[128 * 32];
    __shared__ unsigned short Bs[128 * 32];
    const int t  = threadIdx.x;
    const int w  = t >> 6, l = t & 63;
    const int wr = w >> 1, wc = w & 1;
    const int m0 = blockIdx.y << 7;
    const int n0 = blockIdx.x << 7;

    f32x4 acc[4][4] = {};
    const int nkt = DM >> 5;
    for (int kt = 0; kt < nkt; ++kt) {
        #pragma unroll
        for (int j = 0; j < 2; ++j) {
            const int c0 = j * 256 + w * 64;          // wave-uniform chunk base
            const int cc = c0 + l;                    // per-lane chunk
            const int row = cc >> 2, qq = cc & 3;
            gload16(A  + (size_t)(m0 + row) * DM + kt * 32 + qq * 8, &As[c0 * 8]);
            gload16(Bt + (size_t)(n0 + row) * DM + kt * 32 + qq * 8, &Bs[c0 * 8]);
        }
        __syncthreads();
        short8 af[4], bf_[4];
        #pragma unroll
        for (int mi = 0; mi < 4; ++mi)
            af[mi] = *(short8*)&As[(wr * 64 + mi * 16 + (l & 15)) * 32 + (l >> 4) * 8];
        #pragma unroll
        for (int ni = 0; ni < 4; ++ni)
            bf_[ni] = *(short8*)&Bs[(wc * 64 + ni * 16 + (l & 15)) * 32 + (l >> 4) * 8];
        #pragma unroll
        for (int mi = 0; mi < 4; ++mi)
            #pragma unroll
            for (int ni = 0; ni < 4; ++ni)
                acc[mi][ni] = __builtin_amdgcn_mfma_f32_16x16x32_bf16(
                                  af[mi], bf_[ni], acc[mi][ni], 0, 0, 0);
        __syncthreads();
    }

    const int seg = n0 >> 10;
    const float* bias = (seg == 0) ? bq : (seg == 1) ? bk : bv;
    const float scale = (seg == 0) ? SCALE_Q : 1.0f;
    unsigned short* C = Out + (size_t)seg * MROWS * DM;
    const int ncol0 = (n0 & 1023) + wc * 64;
    float bvv[4];
    #pragma unroll
    for (int ni = 0; ni < 4; ++ni)
        bvv[ni] = bias[ncol0 + ni * 16 + (l & 15)];
    #pragma unroll
    for (int mi = 0; mi < 4; ++mi)
        #pragma unroll
        for (int ni = 0; ni < 4; ++ni) {
            const int gcol = ncol0 + ni * 16 + (l & 15);
            #pragma unroll
            for (int r = 0; r < 4; ++r) {
                const int grow = m0 + wr * 64 + mi * 16 + (l >> 4) * 4 + r;
                C[(size_t)grow * DM + gcol] = f2bf((acc[mi][ni][r] + bvv[ni]) * scale);
            }
        }
}

// ---------------------------------------------------------------------------
// Output projection: 64x128 tile, gload_lds staging, fp32 out.
// ---------------------------------------------------------------------------
__global__ __launch_bounds__(256) void gemm_wo(const unsigned short* __restrict__ A,
                                               const unsigned short* __restrict__ Bt,
                                               float* __restrict__ C)
{
    __shared__ unsigned short As[64 * 32];
    __shared__ unsigned short Bs[128 * 32];
    const int t = threadIdx.x, w = t >> 6, l = t & 63;
    const int wr = w >> 1, wc = w & 1;
    const int m0 = blockIdx.y << 6;
    const int n0 = blockIdx.x << 7;

    f32x4 acc[2][4] = {};
    const int nkt = DM >> 5;
    for (int kt = 0; kt < nkt; ++kt) {
        {
            const int c0 = w * 64;
            const int cc = c0 + l;
            const int row = cc >> 2, qq = cc & 3;
            gload16(A + (size_t)(m0 + row) * DM + kt * 32 + qq * 8, &As[c0 * 8]);
        }
        #pragma unroll
        for (int j = 0; j < 2; ++j) {
            const int c0 = j * 256 + w * 64;
            const int cc = c0 + l;
            const int row = cc >> 2, qq = cc & 3;
            gload16(Bt + (size_t)(n0 + row) * DM + kt * 32 + qq * 8, &Bs[c0 * 8]);
        }
        __syncthreads();
        short8 af[2], bf_[4];
        #pragma unroll
        for (int mi = 0; mi < 2; ++mi)
            af[mi] = *(short8*)&As[(wr * 32 + mi * 16 + (l & 15)) * 32 + (l >> 4) * 8];
        #pragma unroll
        for (int ni = 0; ni < 4; ++ni)
            bf_[ni] = *(short8*)&Bs[(wc * 64 + ni * 16 + (l & 15)) * 32 + (l >> 4) * 8];
        #pragma unroll
        for (int mi = 0; mi < 2; ++mi)
            #pragma unroll
            for (int ni = 0; ni < 4; ++ni)
                acc[mi][ni] = __builtin_amdgcn_mfma_f32_16x16x32_bf16(
                                  af[mi], bf_[ni], acc[mi][ni], 0, 0, 0);
        __syncthreads();
    }
    #pragma unroll
    for (int mi = 0; mi < 2; ++mi)
        #pragma unroll
        for (int ni = 0; ni < 4; ++ni) {
            const int gcol = n0 + wc * 64 + ni * 16 + (l & 15);
            #pragma unroll
            for (int r = 0; r < 4; ++r) {
                const int grow = m0 + wr * 32 + mi * 16 + (l >> 4) * 4 + r;
                C[(size_t)grow * DM + gcol] = acc[mi][ni][r];
            }
        }
}

// ---------------------------------------------------------------------------
// Register-direct bf16-MFMA flash attention. QB=32, ONE wave per block,
// 2048 blocks. K fragments loaded straight from global (A-layout == contiguous
// 16B), V from pre-transposed Vt. ZERO LDS ops / barriers in the main loop
// (only 6 shfls). Softmax in 2^x domain, max tree, T13 defer-rescale,
// K prefetch 1 iter ahead, T1 XCD-chunked swizzle, T5 setprio around MFMA.
// ---------------------------------------------------------------------------
__global__ __launch_bounds__(64, 2) void attn_reg(const unsigned short* __restrict__ Qg,
                                                  const unsigned short* __restrict__ Kg,
                                                  const unsigned short* __restrict__ Vtg,
                                                  unsigned short* __restrict__ Og)
{
    __shared__ unsigned short ob[32][72];
    const int l   = threadIdx.x;
    const int l31 = l & 31;
    const int hi  = l >> 5;

    // XCD-chunked swizzle: 2048 blocks, 8 XCDs -> 4 heads x 64 q-tiles each
    const int f   = blockIdx.x;
    const int xcd = f & 7;
    const int pos = f >> 3;               // 0..255
    const int bh  = xcd * 4 + (pos >> 6); // 4 (b,h) per XCD
    int qt = pos & 63;
    if ((pos >> 6) & 1) qt = 63 - qt;     // long/short causal pairing
    const int b = bh >> 4;
    const int h = bh & 15;

    const int qb = qt << 5;               // 32 q-rows per block
    const size_t rb0 = (size_t)b * NC;
    const int hd = h * DH;

    const unsigned short* Kbase = Kg + rb0 * DM + hd;            // [n][64] rows
    const unsigned short* Vbase = Vtg + (size_t)bh * 64 * NC;    // [d][n] rows

    // Q fragments (pre-scaled by 0.125*log2e in projection)
    const unsigned short* qp = Qg + (rb0 + qb + l31) * DM + hd + hi * 8;
    short8 fq[4];
    #pragma unroll
    for (int c = 0; c < 4; ++c)
        fq[c] = *(const short8*)(qp + c * 16);

    f32x16 o0 = fzero16(), o1 = fzero16();
    float mrun = -1e30f, lrun = 0.f;
    const bool bottom = (qb >= NC / 2);
    const int nkv = bottom ? ((qt + 2) >> 1) : 16;

    // K fragments: A row = lane&31, k = (lane>>5)*8+e  -> contiguous 16B/lane
    short8 kA[4], kB[4];
    {
        const unsigned short* ka = Kbase + (size_t)(l31) * DM + hi * 8;
        const unsigned short* kb_ = Kbase + (size_t)(32 + l31) * DM + hi * 8;
        #pragma unroll
        for (int c = 0; c < 4; ++c) {
            kA[c] = *(const short8*)(ka + c * 16);
            kB[c] = *(const short8*)(kb_ + c * 16);
        }
    }

    for (int it = 0; it < nkv; ++it) {
        const int kb = it * KVT;
        // ---- V fragments for this tile (latency hides under softmax) ----
        short8 vA[4], vB[4];
        {
            const unsigned short* va = Vbase + (size_t)l31 * NC + kb + hi * 8;
            const unsigned short* vb = Vbase + (size_t)(32 + l31) * NC + kb + hi * 8;
            #pragma unroll
            for (int c = 0; c < 4; ++c) {
                vA[c] = *(const short8*)(va + c * 16);
                vB[c] = *(const short8*)(vb + c * 16);
            }
        }
        // ---- S^T = K . Q^T ----
        f32x16 s0 = fzero16(), s1 = fzero16();
        __builtin_amdgcn_s_setprio(1);
        #pragma unroll
        for (int c = 0; c < 4; ++c) {
            s0 = __builtin_amdgcn_mfma_f32_32x32x16_bf16(kA[c], fq[c], s0, 0, 0, 0);
            s1 = __builtin_amdgcn_mfma_f32_32x32x16_bf16(kB[c], fq[c], s1, 0, 0, 0);
        }
        __builtin_amdgcn_s_setprio(0);
        // ---- prefetch next K tile into regs ----
        if (it + 1 < nkv) {
            const unsigned short* ka = Kbase + (size_t)((it + 1) * KVT + l31) * DM + hi * 8;
            const unsigned short* kb2 = Kbase + (size_t)((it + 1) * KVT + 32 + l31) * DM + hi * 8;
            #pragma unroll
            for (int c = 0; c < 4; ++c) {
                kA[c] = *(const short8*)(ka + c * 16);
                kB[c] = *(const short8*)(kb2 + c * 16);
            }
        }
        // ---- causal mask (bottom half, diagonal-crossing tile) ----
        if (bottom && (kb + KVT - 1 > qb)) {
            const int qg = qb + l31;
            #pragma unroll
            for (int r = 0; r < 16; ++r) {
                const int kk = (r & 3) + 8 * (r >> 2) + 4 * hi;
                if (kb + kk > qg)      s0[r] = -1e30f;
                if (kb + 32 + kk > qg) s1[r] = -1e30f;
            }
        }
        // ---- max tree ----
        float tm[16];
        #pragma unroll
        for (int r = 0; r < 16; ++r) tm[r] = fmaxf(s0[r], s1[r]);
        #pragma unroll
        for (int st = 8; st > 0; st >>= 1)
            #pragma unroll
            for (int r = 0; r < 8; ++r)
                if (r < st) tm[r] = fmaxf(tm[r], tm[r + st]);
        float pm = fmaxf(tm[0], __shfl_xor(tm[0], 32));
        // ---- T13 defer-rescale ----
        if (!__all(pm - mrun <= 8.f)) {
            const float mnew = fmaxf(mrun, pm);
            const float corr = exp2v(mrun - mnew);
            mrun = mnew;
            lrun *= corr;
            #pragma unroll
            for (int i = 0; i < 16; ++i) { o0[i] *= corr; o1[i] *= corr; }
        }
        float rs = 0.f;
        #pragma unroll
        for (int r = 0; r < 16; ++r) { s0[r] = exp2v(s0[r] - mrun); rs += s0[r]; }
        #pragma unroll
        for (int r = 0; r < 16; ++r) { s1[r] = exp2v(s1[r] - mrun); rs += s1[r]; }
        rs += __shfl_xor(rs, 32);
        lrun += rs;
        // ---- P -> bf16 B-frags, PV accumulate (O^T = V^T . P^T) ----
        __builtin_amdgcn_s_setprio(1);
        #pragma unroll
        for (int kc = 0; kc < 4; ++kc) {
            const f32x16 src = (kc < 2) ? s0 : s1;
            const int rbase = (kc & 1) * 8;
            unsigned A01 = pkbf16(src[rbase + 0], src[rbase + 1]);
            unsigned A23 = pkbf16(src[rbase + 2], src[rbase + 3]);
            unsigned A45 = pkbf16(src[rbase + 4], src[rbase + 5]);
            unsigned A67 = pkbf16(src[rbase + 6], src[rbase + 7]);
            unsigned s01 = (unsigned)__shfl_xor((int)A01, 32);
            unsigned s23 = (unsigned)__shfl_xor((int)A23, 32);
            unsigned s45 = (unsigned)__shfl_xor((int)A45, 32);
            unsigned s67 = (unsigned)__shfl_xor((int)A67, 32);
            short8 fp = hi ? mk8(s45, s67, A45, A67)
                           : mk8(A01, A23, s01, s23);
            o0 = __builtin_amdgcn_mfma_f32_32x32x16_bf16(vA[kc], fp, o0, 0, 0, 0);
            o1 = __builtin_amdgcn_mfma_f32_32x32x16_bf16(vB[kc], fp, o1, 0, 0, 0);
        }
        __builtin_amdgcn_s_setprio(0);
    }

    // ---- epilogue: normalize, bounce O^T through LDS (single wave) ----
    const float inv = 1.f / lrun;
    {
        unsigned short* reg = &ob[l31][0];
        #pragma unroll
        for (int r = 0; r < 16; ++r) {
            const int dd = (r & 3) + 8 * (r >> 2) + 4 * hi;
            reg[dd]      = f2bf(o0[r] * inv);
            reg[dd + 32] = f2bf(o1[r] * inv);
        }
    }
    {
        const int row = l >> 1, seg = l & 1;
        const unsigned short* src = &ob[row][seg * 32];
        unsigned short* dst = Og + (rb0 + qb + row) * DM + hd + seg * 32;
        #pragma unroll
        for (int i = 0; i < 4; ++i)
            *(short8*)(dst + i * 8) = *(const short8*)(src + i * 8);
    }
}

// ---------------------------------------------------------------------------
extern "C" void kernel_launch(void* const* d_in, const int* in_sizes, int n_in,
                              void* d_out, int out_size, void* d_ws, size_t ws_size,
                              hipStream_t stream)
{
    const float* x  = (const float*)d_in[0];
    const float* Wq = (const float*)d_in[1];
    const float* bq = (const float*)d_in[2];
    const float* Wk = (const float*)d_in[3];
    const float* bk = (const float*)d_in[4];
    const float* Wv = (const float*)d_in[5];
    const float* bv = (const float*)d_in[6];
    const float* Wo = (const float*)d_in[7];
    float* out = (float*)d_out;

    char* ws = (char*)d_ws;
    const size_t szA = (size_t)MROWS * DM * 2;   // 8.39 MB
    const size_t szW = (size_t)DM * DM * 2;      // 2.10 MB
    unsigned short* xb  = (unsigned short*)(ws);
    unsigned short* wqT = (unsigned short*)(ws + szA);            // wq/wk/wv/wo contiguous
    unsigned short* woT = (unsigned short*)(ws + szA + 3 * szW);
    unsigned short* qb_ = (unsigned short*)(ws + szA + 4 * szW);  // q/k/v contiguous
    unsigned short* kb_ = (unsigned short*)(ws + 2 * szA + 4 * szW);
    unsigned short* vb_ = (unsigned short*)(ws + 3 * szA + 4 * szW);
    unsigned short* ab_ = (unsigned short*)(ws + 4 * szA + 4 * szW);
    unsigned short* vt_ = xb;   // reuse x buffer: consumed once gemm_qkv is done

    cvt_x<<<dim3(MROWS * DM / 8 / 256), 256, 0, stream>>>(x, xb, MROWS * DM / 8);
    cvt_w4<<<dim3(16, 16, 4), 256, 0, stream>>>(Wq, Wk, Wv, Wo, wqT);

    gemm_qkv<<<dim3(24, 32), 256, 0, stream>>>(xb, wqT, bq, bk, bv, qb_);
    cvt_vT<<<dim3(32, 32), 256, 0, stream>>>(vb_, vt_);
    attn_reg<<<dim3(2048), 64, 0, stream>>>(qb_, kb_, vt_, ab_);
    gemm_wo<<<dim3(8, 64), 256, 0, stream>>>(ab_, woT, out);
}

// Round 7
// 124.048 us; speedup vs baseline: 1.2779x; 1.2779x over previous
//
#include <hip/hip_runtime.h>
#include <hip/hip_bf16.h>

#define NH 16
#define DH 64
#define DM 1024
#define NC 2048
#define MROWS 4096
#define KVT 64

#define SCALE_Q 0.180336880f   // 0.125 * log2(e): softmax done in 2^x domain

typedef __attribute__((ext_vector_type(8))) short short8;
typedef __attribute__((ext_vector_type(4))) float f32x4;
typedef __attribute__((ext_vector_type(16))) float f32x16;
typedef __attribute__((ext_vector_type(4))) unsigned int uint4e;

__device__ __forceinline__ unsigned pkbf16(float a, float b) {
    unsigned r;
    asm("v_cvt_pk_bf16_f32 %0, %1, %2" : "=v"(r) : "v"(a), "v"(b));
    return r;
}
__device__ __forceinline__ unsigned short f2bf(float x) {
    return (unsigned short)(pkbf16(x, x) & 0xffffu);
}
__device__ __forceinline__ float exp2v(float x) {   // 2^x, v_exp_f32
    float r;
    asm("v_exp_f32 %0, %1" : "=v"(r) : "v"(x));
    return r;
}
__device__ __forceinline__ f32x16 fzero16() {
    f32x16 r;
    #pragma unroll
    for (int i = 0; i < 16; ++i) r[i] = 0.f;
    return r;
}
__device__ __forceinline__ short8 mk8(unsigned w0, unsigned w1, unsigned w2, unsigned w3) {
    uint4e u = {w0, w1, w2, w3};
    return __builtin_bit_cast(short8, u);
}
// async global->LDS, 16B per lane; lds dest = wave-uniform base + lane*16 (HW)
__device__ __forceinline__ void gload16(const unsigned short* g, unsigned short* l) {
    __builtin_amdgcn_global_load_lds(
        (const __attribute__((address_space(1))) void*)g,
        (__attribute__((address_space(3))) void*)l, 16, 0, 0);
}

// ---------------------------------------------------------------------------
// fp32 -> bf16 elementwise convert (8 elems/thread)
// ---------------------------------------------------------------------------
__global__ __launch_bounds__(256) void cvt_x(const float* __restrict__ in,
                                             unsigned short* __restrict__ out, int n8)
{
    int i = blockIdx.x * 256 + threadIdx.x;
    if (i >= n8) return;
    const float4 a = ((const float4*)in)[i * 2];
    const float4 b = ((const float4*)in)[i * 2 + 1];
    uint4e u = {pkbf16(a.x, a.y), pkbf16(a.z, a.w), pkbf16(b.x, b.y), pkbf16(b.z, b.w)};
    ((uint4e*)out)[i] = u;
}

// ---------------------------------------------------------------------------
// All 4 weights: W[K][N] fp32 -> Wt[N][K] bf16, fused (blockIdx.z = which W)
// ---------------------------------------------------------------------------
__global__ __launch_bounds__(256) void cvt_w4(const float* __restrict__ W0,
                                              const float* __restrict__ W1,
                                              const float* __restrict__ W2,
                                              const float* __restrict__ W3,
                                              unsigned short* __restrict__ Wt4)
{
    __shared__ unsigned short T[64][72];
    const int z = blockIdx.z;
    const float* W = (z == 0) ? W0 : (z == 1) ? W1 : (z == 2) ? W2 : W3;
    unsigned short* Wt = Wt4 + (size_t)z * DM * DM;
    const int t = threadIdx.x;
    const int r = t >> 2, s = t & 3;
    const int bi = blockIdx.y;
    const int bj = blockIdx.x;
    const float* src = W + (size_t)(bi * 64 + r) * DM + bj * 64 + s * 16;
    float4 f0 = ((const float4*)src)[0];
    float4 f1 = ((const float4*)src)[1];
    float4 f2 = ((const float4*)src)[2];
    float4 f3 = ((const float4*)src)[3];
    uint2 u;
    u.x = pkbf16(f0.x, f0.y); u.y = pkbf16(f0.z, f0.w); *(uint2*)&T[r][s * 16]      = u;
    u.x = pkbf16(f1.x, f1.y); u.y = pkbf16(f1.z, f1.w); *(uint2*)&T[r][s * 16 + 4]  = u;
    u.x = pkbf16(f2.x, f2.y); u.y = pkbf16(f2.z, f2.w); *(uint2*)&T[r][s * 16 + 8]  = u;
    u.x = pkbf16(f3.x, f3.y); u.y = pkbf16(f3.z, f3.w); *(uint2*)&T[r][s * 16 + 12] = u;
    __syncthreads();
    unsigned short vals[16];
    #pragma unroll
    for (int j = 0; j < 16; ++j) vals[j] = T[s * 16 + j][r];
    unsigned short* dst = Wt + (size_t)(bj * 64 + r) * DM + bi * 64 + s * 16;
    *(short8*)(dst)     = *(short8*)&vals[0];
    *(short8*)(dst + 8) = *(short8*)&vals[8];
}

// ---------------------------------------------------------------------------
// Fused QKV projection (m97 structure): 128x128 tile, BK=32, 4 waves,
// global_load_lds width-16 staging into LINEAR LDS [128][32] shorts.
// Q pre-scaled by SCALE_Q. V segment written TRANSPOSED to Vt[bh][d][n].
// ---------------------------------------------------------------------------
__global__ __launch_bounds__(256) void gemm_qkv(const unsigned short* __restrict__ A,
                                                const unsigned short* __restrict__ Bt,
                                                const float* __restrict__ bq,
                                                const float* __restrict__ bk,
                                                const float* __restrict__ bv,
                                                unsigned short* __restrict__ Out)
{
    __shared__ unsigned short As[128 * 32];
    __shared__ unsigned short Bs[128 * 32];
    const int t  = threadIdx.x;
    const int w  = t >> 6, l = t & 63;
    const int wr = w >> 1, wc = w & 1;
    const int m0 = blockIdx.y << 7;
    const int n0 = blockIdx.x << 7;

    f32x4 acc[4][4] = {};
    const int nkt = DM >> 5;
    for (int kt = 0; kt < nkt; ++kt) {
        #pragma unroll
        for (int j = 0; j < 2; ++j) {
            const int c0 = j * 256 + w * 64;          // wave-uniform chunk base
            const int cc = c0 + l;                    // per-lane chunk
            const int row = cc >> 2, qq = cc & 3;
            gload16(A  + (size_t)(m0 + row) * DM + kt * 32 + qq * 8, &As[c0 * 8]);
            gload16(Bt + (size_t)(n0 + row) * DM + kt * 32 + qq * 8, &Bs[c0 * 8]);
        }
        __syncthreads();
        short8 af[4], bf_[4];
        #pragma unroll
        for (int mi = 0; mi < 4; ++mi)
            af[mi] = *(short8*)&As[(wr * 64 + mi * 16 + (l & 15)) * 32 + (l >> 4) * 8];
        #pragma unroll
        for (int ni = 0; ni < 4; ++ni)
            bf_[ni] = *(short8*)&Bs[(wc * 64 + ni * 16 + (l & 15)) * 32 + (l >> 4) * 8];
        #pragma unroll
        for (int mi = 0; mi < 4; ++mi)
            #pragma unroll
            for (int ni = 0; ni < 4; ++ni)
                acc[mi][ni] = __builtin_amdgcn_mfma_f32_16x16x32_bf16(
                                  af[mi], bf_[ni], acc[mi][ni], 0, 0, 0);
        __syncthreads();
    }

    const int seg = n0 >> 10;
    const float* bias = (seg == 0) ? bq : (seg == 1) ? bk : bv;
    const float scale = (seg == 0) ? SCALE_Q : 1.0f;
    const int ncol0 = (n0 & 1023) + wc * 64;
    float bvv[4];
    #pragma unroll
    for (int ni = 0; ni < 4; ++ni)
        bvv[ni] = bias[ncol0 + ni * 16 + (l & 15)];

    if (seg == 2) {
        // V: write transposed Vt[bh][d][n] (bh = b*16+h)
        unsigned short* vt = Out + 2 * (size_t)MROWS * DM;
        #pragma unroll
        for (int mi = 0; mi < 4; ++mi)
            #pragma unroll
            for (int ni = 0; ni < 4; ++ni) {
                const int gcol = ncol0 + ni * 16 + (l & 15);
                const int h_ = gcol >> 6, d_ = gcol & 63;
                #pragma unroll
                for (int r = 0; r < 4; ++r) {
                    const int grow = m0 + wr * 64 + mi * 16 + (l >> 4) * 4 + r;
                    const int b_ = grow >> 11, n_ = grow & 2047;
                    vt[(((size_t)b_ * 16 + h_) * 64 + d_) * NC + n_] =
                        f2bf(acc[mi][ni][r] + bvv[ni]);
                }
            }
    } else {
        unsigned short* C = Out + (size_t)seg * MROWS * DM;
        #pragma unroll
        for (int mi = 0; mi < 4; ++mi)
            #pragma unroll
            for (int ni = 0; ni < 4; ++ni) {
                const int gcol = ncol0 + ni * 16 + (l & 15);
                #pragma unroll
                for (int r = 0; r < 4; ++r) {
                    const int grow = m0 + wr * 64 + mi * 16 + (l >> 4) * 4 + r;
                    C[(size_t)grow * DM + gcol] = f2bf((acc[mi][ni][r] + bvv[ni]) * scale);
                }
            }
    }
}

// ---------------------------------------------------------------------------
// Output projection: 64x128 tile, gload_lds staging, fp32 out.
// ---------------------------------------------------------------------------
__global__ __launch_bounds__(256) void gemm_wo(const unsigned short* __restrict__ A,
                                               const unsigned short* __restrict__ Bt,
                                               float* __restrict__ C)
{
    __shared__ unsigned short As[64 * 32];
    __shared__ unsigned short Bs[128 * 32];
    const int t = threadIdx.x, w = t >> 6, l = t & 63;
    const int wr = w >> 1, wc = w & 1;
    const int m0 = blockIdx.y << 6;
    const int n0 = blockIdx.x << 7;

    f32x4 acc[2][4] = {};
    const int nkt = DM >> 5;
    for (int kt = 0; kt < nkt; ++kt) {
        {
            const int c0 = w * 64;
            const int cc = c0 + l;
            const int row = cc >> 2, qq = cc & 3;
            gload16(A + (size_t)(m0 + row) * DM + kt * 32 + qq * 8, &As[c0 * 8]);
        }
        #pragma unroll
        for (int j = 0; j < 2; ++j) {
            const int c0 = j * 256 + w * 64;
            const int cc = c0 + l;
            const int row = cc >> 2, qq = cc & 3;
            gload16(Bt + (size_t)(n0 + row) * DM + kt * 32 + qq * 8, &Bs[c0 * 8]);
        }
        __syncthreads();
        short8 af[2], bf_[4];
        #pragma unroll
        for (int mi = 0; mi < 2; ++mi)
            af[mi] = *(short8*)&As[(wr * 32 + mi * 16 + (l & 15)) * 32 + (l >> 4) * 8];
        #pragma unroll
        for (int ni = 0; ni < 4; ++ni)
            bf_[ni] = *(short8*)&Bs[(wc * 64 + ni * 16 + (l & 15)) * 32 + (l >> 4) * 8];
        #pragma unroll
        for (int mi = 0; mi < 2; ++mi)
            #pragma unroll
            for (int ni = 0; ni < 4; ++ni)
                acc[mi][ni] = __builtin_amdgcn_mfma_f32_16x16x32_bf16(
                                  af[mi], bf_[ni], acc[mi][ni], 0, 0, 0);
        __syncthreads();
    }
    #pragma unroll
    for (int mi = 0; mi < 2; ++mi)
        #pragma unroll
        for (int ni = 0; ni < 4; ++ni) {
            const int gcol = n0 + wc * 64 + ni * 16 + (l & 15);
            #pragma unroll
            for (int r = 0; r < 4; ++r) {
                const int grow = m0 + wr * 32 + mi * 16 + (l >> 4) * 4 + r;
                C[(size_t)grow * DM + gcol] = acc[mi][ni][r];
            }
        }
}

// ---------------------------------------------------------------------------
// bf16-MFMA flash attention, LDS-staged via global_load_lds + T2 XOR swizzle.
// QB=64, 2 waves/block, 1024 blocks. K tile [64][128B] and Vt tile [64][128B]
// staged by DMA (no ds_write, no staging VALU); 16B slot index XORed with
// (row&7) on the READ side, inverse-XOR applied to the GLOBAL source address
// (rule #21: linear dest + pre-swizzled source + swizzled read).
// Double-buffered, 1 barrier/iter. Softmax: 2^x domain, max tree, T13.
// ---------------------------------------------------------------------------
__global__ __launch_bounds__(128, 2) void attn_lds(const unsigned short* __restrict__ Qg,
                                                   const unsigned short* __restrict__ Kg,
                                                   const unsigned short* __restrict__ Vtg,
                                                   unsigned short* __restrict__ Og)
{
    __shared__ unsigned short KS[2][4096];   // 2 x 8KB: [row 0..63][8 slots x 8 shorts]
    __shared__ unsigned short VS[2][4096];
    const int t   = threadIdx.x;
    const int w   = t >> 6;          // 0..1
    const int l   = t & 63;
    const int l31 = l & 31;
    const int hi  = l >> 5;

    // T1 XCD-chunked swizzle: 1024 blocks, 8 XCDs -> 4 (b,h) x 32 q-tiles each
    const int f   = blockIdx.x;
    const int xcd = f & 7;
    const int pos = f >> 3;               // 0..127
    const int bh  = xcd * 4 + (pos >> 5);
    int qt = pos & 31;
    if ((pos >> 5) & 1) qt = 31 - qt;     // long/short causal pairing
    const int b = bh >> 4;
    const int h = bh & 15;

    const int qb = qt << 6;               // 64 q-rows per block
    const int wq = qb + w * 32;           // this wave's 32 q-rows
    const size_t rb0 = (size_t)b * NC;
    const int hd = h * DH;

    // Q fragments (pre-scaled by 0.125*log2e in projection)
    const unsigned short* qp = Qg + (rb0 + wq + l31) * DM + hd + hi * 8;
    short8 fq[4];
    #pragma unroll
    for (int c = 0; c < 4; ++c)
        fq[c] = *(const short8*)(qp + c * 16);

    f32x16 o0 = fzero16(), o1 = fzero16();
    float mrun = -1e30f, lrun = 0.f;
    const bool bottom = (qb >= NC / 2);
    const int nkv = bottom ? (qt + 1) : 16;

    const unsigned short* Vbase = Vtg + (size_t)bh * 64 * NC;

    // stage one KV tile: each wave issues 4 K + 4 V gload16 (chunks w*4..w*4+3)
    auto stage = [&](int it, int buf) {
        const int kb = it * KVT;
        #pragma unroll
        for (int j = 0; j < 4; ++j) {
            const int jj  = w * 4 + j;            // 0..7 (wave-uniform)
            const int p   = jj * 64 + l;          // lane-chunk 0..511
            const int row = p >> 3;               // 0..63
            const int slot = (p & 7) ^ (row & 7); // inverse swizzle on SOURCE
            gload16(Kg + (size_t)(rb0 + kb + row) * DM + hd + slot * 8,
                    &KS[buf][jj * 512]);
            gload16(Vbase + (size_t)row * NC + kb + slot * 8,
                    &VS[buf][jj * 512]);
        }
    };

    stage(0, 0);
    __syncthreads();

    for (int it = 0; it < nkv; ++it) {
        const int kb = it * KVT;
        const int cur = it & 1;
        if (it + 1 < nkv) stage(it + 1, cur ^ 1);   // DMA overlaps compute

        // ---- K fragments: swizzled ds_read_b128, conflict-free ----
        const unsigned short* Kb = &KS[cur][0];
        short8 kf[2][4];
        #pragma unroll
        for (int half = 0; half < 2; ++half) {
            const int row = half * 32 + l31;
            const int rx  = row & 7;
            #pragma unroll
            for (int c = 0; c < 4; ++c) {
                const int slot = (c * 2 + hi) ^ rx;
                kf[half][c] = *(const short8*)(Kb + row * 64 + slot * 8);
            }
        }
        // ---- S^T = K . Q^T ----
        f32x16 s0 = fzero16(), s1 = fzero16();
        __builtin_amdgcn_s_setprio(1);
        #pragma unroll
        for (int c = 0; c < 4; ++c) {
            s0 = __builtin_amdgcn_mfma_f32_32x32x16_bf16(kf[0][c], fq[c], s0, 0, 0, 0);
            s1 = __builtin_amdgcn_mfma_f32_32x32x16_bf16(kf[1][c], fq[c], s1, 0, 0, 0);
        }
        __builtin_amdgcn_s_setprio(0);
        // ---- causal mask (bottom half, diagonal-crossing tile) ----
        if (bottom && (kb + KVT - 1 > wq)) {
            const int qg = wq + l31;
            #pragma unroll
            for (int r = 0; r < 16; ++r) {
                const int kk = (r & 3) + 8 * (r >> 2) + 4 * hi;
                if (kb + kk > qg)      s0[r] = -1e30f;
                if (kb + 32 + kk > qg) s1[r] = -1e30f;
            }
        }
        // ---- max tree ----
        float tm[16];
        #pragma unroll
        for (int r = 0; r < 16; ++r) tm[r] = fmaxf(s0[r], s1[r]);
        #pragma unroll
        for (int st = 8; st > 0; st >>= 1)
            #pragma unroll
            for (int r = 0; r < 8; ++r)
                if (r < st) tm[r] = fmaxf(tm[r], tm[r + st]);
        float pm = fmaxf(tm[0], __shfl_xor(tm[0], 32));
        // ---- T13 defer-rescale ----
        if (!__all(pm - mrun <= 8.f)) {
            const float mnew = fmaxf(mrun, pm);
            const float corr = exp2v(mrun - mnew);
            mrun = mnew;
            lrun *= corr;
            #pragma unroll
            for (int i = 0; i < 16; ++i) { o0[i] *= corr; o1[i] *= corr; }
        }
        float rs = 0.f;
        #pragma unroll
        for (int r = 0; r < 16; ++r) { s0[r] = exp2v(s0[r] - mrun); rs += s0[r]; }
        #pragma unroll
        for (int r = 0; r < 16; ++r) { s1[r] = exp2v(s1[r] - mrun); rs += s1[r]; }
        rs += __shfl_xor(rs, 32);
        lrun += rs;
        // ---- P -> bf16 B-frags, PV accumulate (O^T = V^T . P^T) ----
        const unsigned short* Vb = &VS[cur][0];
        __builtin_amdgcn_s_setprio(1);
        #pragma unroll
        for (int kc = 0; kc < 4; ++kc) {
            const f32x16 src = (kc < 2) ? s0 : s1;
            const int rbase = (kc & 1) * 8;
            unsigned A01 = pkbf16(src[rbase + 0], src[rbase + 1]);
            unsigned A23 = pkbf16(src[rbase + 2], src[rbase + 3]);
            unsigned A45 = pkbf16(src[rbase + 4], src[rbase + 5]);
            unsigned A67 = pkbf16(src[rbase + 6], src[rbase + 7]);
            unsigned s01 = (unsigned)__shfl_xor((int)A01, 32);
            unsigned s23 = (unsigned)__shfl_xor((int)A23, 32);
            unsigned s45 = (unsigned)__shfl_xor((int)A45, 32);
            unsigned s67 = (unsigned)__shfl_xor((int)A67, 32);
            short8 fp = hi ? mk8(s45, s67, A45, A67)
                           : mk8(A01, A23, s01, s23);
            const int slot = (kc * 2 + hi);
            const int r0_ = l31, r1_ = 32 + l31;
            short8 v0 = *(const short8*)(Vb + r0_ * 64 + (slot ^ (r0_ & 7)) * 8);
            short8 v1 = *(const short8*)(Vb + r1_ * 64 + (slot ^ (r1_ & 7)) * 8);
            o0 = __builtin_amdgcn_mfma_f32_32x32x16_bf16(v0, fp, o0, 0, 0, 0);
            o1 = __builtin_amdgcn_mfma_f32_32x32x16_bf16(v1, fp, o1, 0, 0, 0);
        }
        __builtin_amdgcn_s_setprio(0);

        __syncthreads();   // drains DMA for next buf; all reads of cur done
    }

    // ---- epilogue: normalize, bounce O^T (bf16) through LDS, coalesced store
    const float inv = 1.f / lrun;
    unsigned short* obuf = (unsigned short*)&KS[0][0];  // [64][72] shorts (9216B)
    {
        unsigned short* reg = obuf + (size_t)(w * 32 + l31) * 72;
        #pragma unroll
        for (int r = 0; r < 16; ++r) {
            const int dd = (r & 3) + 8 * (r >> 2) + 4 * hi;
            reg[dd]      = f2bf(o0[r] * inv);
            reg[dd + 32] = f2bf(o1[r] * inv);
        }
    }
    __syncthreads();
    {
        const int row = t >> 1, seg = t & 1;
        const unsigned short* src = obuf + (size_t)row * 72 + seg * 32;
        unsigned short* dst = Og + (rb0 + qb + row) * DM + hd + seg * 32;
        #pragma unroll
        for (int i = 0; i < 4; ++i)
            *(short8*)(dst + i * 8) = *(const short8*)(src + i * 8);
    }
}

// ---------------------------------------------------------------------------
extern "C" void kernel_launch(void* const* d_in, const int* in_sizes, int n_in,
                              void* d_out, int out_size, void* d_ws, size_t ws_size,
                              hipStream_t stream)
{
    const float* x  = (const float*)d_in[0];
    const float* Wq = (const float*)d_in[1];
    const float* bq = (const float*)d_in[2];
    const float* Wk = (const float*)d_in[3];
    const float* bk = (const float*)d_in[4];
    const float* Wv = (const float*)d_in[5];
    const float* bv = (const float*)d_in[6];
    const float* Wo = (const float*)d_in[7];
    float* out = (float*)d_out;

    char* ws = (char*)d_ws;
    const size_t szA = (size_t)MROWS * DM * 2;   // 8.39 MB
    const size_t szW = (size_t)DM * DM * 2;      // 2.10 MB
    unsigned short* xb  = (unsigned short*)(ws);
    unsigned short* wqT = (unsigned short*)(ws + szA);            // wq/wk/wv/wo contiguous
    unsigned short* woT = (unsigned short*)(ws + szA + 3 * szW);
    unsigned short* qb_ = (unsigned short*)(ws + szA + 4 * szW);  // q/k/vt contiguous
    unsigned short* kb_ = (unsigned short*)(ws + 2 * szA + 4 * szW);
    unsigned short* vt_ = (unsigned short*)(ws + 3 * szA + 4 * szW);  // Vt[bh][d][n]
    unsigned short* ab_ = (unsigned short*)(ws + 4 * szA + 4 * szW);

    cvt_x<<<dim3(MROWS * DM / 8 / 256), 256, 0, stream>>>(x, xb, MROWS * DM / 8);
    cvt_w4<<<dim3(16, 16, 4), 256, 0, stream>>>(Wq, Wk, Wv, Wo, wqT);

    gemm_qkv<<<dim3(24, 32), 256, 0, stream>>>(xb, wqT, bq, bk, bv, qb_);
    attn_lds<<<dim3(1024), 128, 0, stream>>>(qb_, kb_, vt_, ab_);
    gemm_wo<<<dim3(8, 64), 256, 0, stream>>>(ab_, woT, out);
}